// Round 1
// baseline (541.544 us; speedup 1.0000x reference)
//
#include <hip/hip_runtime.h>

typedef __bf16 bf16;
typedef __attribute__((ext_vector_type(8))) __bf16 bf16x8;
typedef __attribute__((ext_vector_type(4))) float f32x4;

static __device__ __forceinline__ int swz4(int r) { return (r & 3) ^ ((r >> 2) & 3); }

static __device__ __forceinline__ void async_cp16(void* lds, const void* g) {
  __builtin_amdgcn_global_load_lds((__attribute__((address_space(1))) void*)g,
                                   (__attribute__((address_space(3))) void*)lds,
                                   16, 0, 0);
}

static __device__ __forceinline__ f32x4 mfma16(bf16x8 a, bf16x8 b, f32x4 c) {
  return __builtin_amdgcn_mfma_f32_16x16x32_bf16(a, b, c, 0, 0, 0);
}

static __device__ __forceinline__ unsigned short bfbits(float f) {
  bf16 b = (bf16)f;
  return __builtin_bit_cast(unsigned short, b);
}

// ---------------- small kernels ----------------

// f32 -> bf16 hi (+ optional lo = residual) conversion, 4 elems/thread
extern "C" __global__ void cvt_kernel(const float* __restrict__ src,
                                      unsigned short* __restrict__ hi,
                                      unsigned short* __restrict__ lo, int n4) {
  int i = blockIdx.x * 256 + threadIdx.x;
  if (i >= n4) return;
  float4 v = ((const float4*)src)[i];
  bf16 b0 = (bf16)v.x, b1 = (bf16)v.y, b2 = (bf16)v.z, b3 = (bf16)v.w;
  ushort4 oh;
  oh.x = __builtin_bit_cast(unsigned short, b0);
  oh.y = __builtin_bit_cast(unsigned short, b1);
  oh.z = __builtin_bit_cast(unsigned short, b2);
  oh.w = __builtin_bit_cast(unsigned short, b3);
  ((ushort4*)hi)[i] = oh;
  if (lo) {
    ushort4 ol;
    ol.x = bfbits(v.x - (float)b0);
    ol.y = bfbits(v.y - (float)b1);
    ol.z = bfbits(v.z - (float)b2);
    ol.w = bfbits(v.w - (float)b3);
    ((ushort4*)lo)[i] = ol;
  }
}

// rope table: rope[s*32+i] = (cos, sin) of s * theta^(-2i/64)
extern "C" __global__ void rope_table_kernel(float2* __restrict__ rope) {
  int idx = blockIdx.x * 256 + threadIdx.x; // 32768
  int s = idx >> 5, i = idx & 31;
  float inv_freq = powf(10000.0f, -(2.0f * (float)i) / 64.0f);
  float ang = (float)s * inv_freq;
  float2 cs;
  cs.x = cosf(ang);
  cs.y = sinf(ang);
  rope[idx] = cs;
}

// rms_norm over rows of 1024 f32; outputs bf16 hi (+ optional lo split)
extern "C" __global__ __launch_bounds__(256) void rmsnorm_kernel(
    const float* __restrict__ x, const float* __restrict__ g,
    unsigned short* __restrict__ yhi, unsigned short* __restrict__ ylo) {
  int row = blockIdx.x;
  int t = threadIdx.x;
  const float4 xv = *(const float4*)(x + (size_t)row * 1024 + t * 4);
  float ss = xv.x * xv.x + xv.y * xv.y + xv.z * xv.z + xv.w * xv.w;
#pragma unroll
  for (int d = 1; d < 64; d <<= 1) ss += __shfl_xor(ss, d, 64);
  __shared__ float red[4];
  if ((t & 63) == 0) red[t >> 6] = ss;
  __syncthreads();
  float tot = red[0] + red[1] + red[2] + red[3];
  float inv = 1.0f / sqrtf(tot * (1.0f / 1024.0f) + 1e-5f);
  const float4 gv = *(const float4*)(g + t * 4);
  float y0 = xv.x * gv.x * inv, y1 = xv.y * gv.y * inv;
  float y2 = xv.z * gv.z * inv, y3 = xv.w * gv.w * inv;
  bf16 b0 = (bf16)y0, b1 = (bf16)y1, b2 = (bf16)y2, b3 = (bf16)y3;
  ushort4 oh;
  oh.x = __builtin_bit_cast(unsigned short, b0);
  oh.y = __builtin_bit_cast(unsigned short, b1);
  oh.z = __builtin_bit_cast(unsigned short, b2);
  oh.w = __builtin_bit_cast(unsigned short, b3);
  ((ushort4*)yhi)[(size_t)row * 256 + t] = oh;
  if (ylo) {
    ushort4 ol;
    ol.x = bfbits(y0 - (float)b0);
    ol.y = bfbits(y1 - (float)b1);
    ol.z = bfbits(y2 - (float)b2);
    ol.w = bfbits(y3 - (float)b3);
    ((ushort4*)ylo)[(size_t)row * 256 + t] = ol;
  }
}

// ---------------- GEMM: C[M,N] = A[M,K] * B[N,K]^T, 128x128 tile, BK=32 ----------------
// EPI 0: vT store (bf16, transposed per-head v)
// EPI 1: + resF -> f32 outF
// EPI 2: silu(acc) -> bf16 outB
// EPI 3: mulB[idx] = mulB[idx] * acc (bf16 in/out)
// EPI 4: outF[idx] += acc (f32 in/out)
template <int EPI>
__global__ __launch_bounds__(256, 2) void gemm_nt(
    const bf16* __restrict__ A, const bf16* __restrict__ B, int M, int N, int K,
    float* __restrict__ outF, bf16* __restrict__ outB,
    const float* __restrict__ resF, bf16* __restrict__ mulB) {
  __shared__ alignas(16) bf16 As[128 * 32];
  __shared__ alignas(16) bf16 Bs[128 * 32];
  const int tid = threadIdx.x;
  const int lane = tid & 63, wave = tid >> 6;
  const int lo = lane & 15, hi = lane >> 4;
  const int wm = wave >> 1, wn = wave & 1;
  const size_t tm = (size_t)blockIdx.y * 128, tn = (size_t)blockIdx.x * 128;
  f32x4 acc[4][4] = {};
  for (int k0 = 0; k0 < K; k0 += 32) {
    __syncthreads();
#pragma unroll
    for (int i2 = 0; i2 < 2; i2++) {
      int p = tid + 256 * i2;
      int row = p >> 2, kcp = p & 3;
      int kcl = kcp ^ swz4(row);
      async_cp16((char*)As + (size_t)p * 16, A + (tm + row) * (size_t)K + k0 + kcl * 8);
      async_cp16((char*)Bs + (size_t)p * 16, B + (tn + row) * (size_t)K + k0 + kcl * 8);
    }
    __syncthreads();
    bf16x8 fa[4], fb[4];
#pragma unroll
    for (int i = 0; i < 4; i++) {
      int ra = wm * 64 + i * 16 + lo;
      fa[i] = *(const bf16x8*)((const char*)As + ra * 64 + ((hi ^ swz4(ra)) << 4));
      int rb = wn * 64 + i * 16 + lo;
      fb[i] = *(const bf16x8*)((const char*)Bs + rb * 64 + ((hi ^ swz4(rb)) << 4));
    }
#pragma unroll
    for (int i = 0; i < 4; i++)
#pragma unroll
      for (int j = 0; j < 4; j++) acc[i][j] = mfma16(fa[i], fb[j], acc[i][j]);
  }
#pragma unroll
  for (int i = 0; i < 4; i++)
#pragma unroll
    for (int j = 0; j < 4; j++)
#pragma unroll
      for (int r = 0; r < 4; r++) {
        size_t m = tm + wm * 64 + i * 16 + hi * 4 + r;
        size_t n = tn + wn * 64 + j * 16 + lo;
        float v = acc[i][j][r];
        if constexpr (EPI == 0) {
          size_t idx = (((m >> 10) * 16 + (n >> 6)) * 64 + (n & 63)) * 1024 + (m & 1023);
          outB[idx] = (bf16)v;
        } else if constexpr (EPI == 1) {
          size_t idx = m * (size_t)N + n;
          outF[idx] = v + resF[idx];
        } else if constexpr (EPI == 2) {
          float sg = 1.0f / (1.0f + __expf(-v));
          outB[m * (size_t)N + n] = (bf16)(v * sg);
        } else if constexpr (EPI == 3) {
          size_t idx = m * (size_t)N + n;
          float gv = (float)mulB[idx];
          mulB[idx] = (bf16)(gv * v);
        } else {
          size_t idx = m * (size_t)N + n;
          outF[idx] = outF[idx] + v;
        }
      }
}

// ---------------- split-precision q/k projection GEMM with fused RoPE ----------------
// C = (Ah+Al)*(Bh+Bl)^T  (3-term), M=4096 N=1024 K=1024; out: roped bf16 hi/lo in (b,h,s,dk)
extern "C" __global__ __launch_bounds__(256, 2) void gemm_qk_kernel(
    const bf16* __restrict__ Ah, const bf16* __restrict__ Al,
    const bf16* __restrict__ Bh, const bf16* __restrict__ Bl,
    const float2* __restrict__ rope, bf16* __restrict__ Oh, bf16* __restrict__ Ol) {
  __shared__ alignas(16) bf16 Ahs[128 * 32], Als[128 * 32], Bhs[128 * 32], Bls[128 * 32];
  const int tid = threadIdx.x;
  const int lane = tid & 63, wave = tid >> 6;
  const int lo = lane & 15, hi = lane >> 4;
  const int wm = wave >> 1, wn = wave & 1;
  const size_t tm = (size_t)blockIdx.y * 128, tn = (size_t)blockIdx.x * 128;
  const int K = 1024;
  f32x4 acc[4][4] = {};
  for (int k0 = 0; k0 < K; k0 += 32) {
    __syncthreads();
#pragma unroll
    for (int i2 = 0; i2 < 2; i2++) {
      int p = tid + 256 * i2;
      int row = p >> 2;
      int kcl = (p & 3) ^ swz4(row);
      size_t ga = (tm + row) * (size_t)K + k0 + kcl * 8;
      size_t gb = (tn + row) * (size_t)K + k0 + kcl * 8;
      async_cp16((char*)Ahs + (size_t)p * 16, Ah + ga);
      async_cp16((char*)Als + (size_t)p * 16, Al + ga);
      async_cp16((char*)Bhs + (size_t)p * 16, Bh + gb);
      async_cp16((char*)Bls + (size_t)p * 16, Bl + gb);
    }
    __syncthreads();
    bf16x8 fah[4], fal[4], fbh[4], fbl[4];
#pragma unroll
    for (int i = 0; i < 4; i++) {
      int ra = wm * 64 + i * 16 + lo;
      int oa = ra * 64 + ((hi ^ swz4(ra)) << 4);
      fah[i] = *(const bf16x8*)((const char*)Ahs + oa);
      fal[i] = *(const bf16x8*)((const char*)Als + oa);
      int rb = wn * 64 + i * 16 + lo;
      int ob = rb * 64 + ((hi ^ swz4(rb)) << 4);
      fbh[i] = *(const bf16x8*)((const char*)Bhs + ob);
      fbl[i] = *(const bf16x8*)((const char*)Bls + ob);
    }
#pragma unroll
    for (int i = 0; i < 4; i++)
#pragma unroll
      for (int j = 0; j < 4; j++) {
        f32x4 a = acc[i][j];
        a = mfma16(fah[i], fbh[j], a);
        a = mfma16(fah[i], fbl[j], a);
        a = mfma16(fal[i], fbh[j], a);
        acc[i][j] = a;
      }
  }
  // fused RoPE epilogue: pair partner = adjacent column = lane^1
#pragma unroll
  for (int i = 0; i < 4; i++)
#pragma unroll
    for (int j = 0; j < 4; j++)
#pragma unroll
      for (int r = 0; r < 4; r++) {
        float v = acc[i][j][r];
        float vp = __shfl_xor(v, 1, 64);
        size_t m = tm + wm * 64 + i * 16 + hi * 4 + r;
        size_t n = tn + wn * 64 + j * 16 + lo;
        int s = (int)(m & 1023);
        int pi = (int)((n & 63) >> 1);
        float2 cs = rope[s * 32 + pi];
        float res = (n & 1) ? (vp * cs.y + v * cs.x) : (v * cs.x - vp * cs.y);
        size_t idx = (((m >> 10) * 16 + (n >> 6)) * 1024 + (m & 1023)) * 64 + (n & 63);
        bf16 hb = (bf16)res;
        Oh[idx] = hb;
        Ol[idx] = (bf16)(res - (float)hb);
      }
}

// ---------------- flash attention (causal), 64-row Q block, 4 waves ----------------
// q/k: (b,h,s,64) bf16 hi/lo ; vT: (b,h,64,s) bf16 ; ctx out: (b,s,h*64+d) bf16
extern "C" __global__ __launch_bounds__(256, 3) void flash_kernel(
    const bf16* __restrict__ qhi, const bf16* __restrict__ qlo,
    const bf16* __restrict__ khi, const bf16* __restrict__ klo,
    const bf16* __restrict__ vT, bf16* __restrict__ ctx) {
  const int qb = blockIdx.x;  // 0..15
  const int bh = blockIdx.y;  // 0..63
  const int wave = threadIdx.x >> 6;
  const int lane = threadIdx.x & 63;
  const int lo = lane & 15, hi = lane >> 4;

  __shared__ alignas(16) bf16 P[4][16][72];

  size_t qoff = ((size_t)bh * 1024 + qb * 64 + wave * 16 + lo) * 64;
  bf16x8 qh[2], ql[2];
#pragma unroll
  for (int ks = 0; ks < 2; ks++) {
    qh[ks] = *(const bf16x8*)(qhi + qoff + ks * 32 + hi * 8);
    ql[ks] = *(const bf16x8*)(qlo + qoff + ks * 32 + hi * 8);
  }
  float mrun[4] = {-1e30f, -1e30f, -1e30f, -1e30f};
  float lrun[4] = {0.f, 0.f, 0.f, 0.f};
  f32x4 o[4] = {};
  const float scale = 0.125f;
  for (int kt = 0; kt <= qb; kt++) {
    f32x4 sv[4];
#pragma unroll
    for (int nb = 0; nb < 4; nb++) {
      f32x4 a = {0.f, 0.f, 0.f, 0.f};
#pragma unroll
      for (int ks = 0; ks < 2; ks++) {
        size_t koff = ((size_t)bh * 1024 + kt * 64 + nb * 16 + lo) * 64 + ks * 32 + hi * 8;
        bf16x8 kh = *(const bf16x8*)(khi + koff);
        bf16x8 kl = *(const bf16x8*)(klo + koff);
        a = mfma16(qh[ks], kh, a);
        a = mfma16(qh[ks], kl, a);
        a = mfma16(ql[ks], kh, a);
      }
      sv[nb] = a;
    }
    const bool mt = (kt == qb);
#pragma unroll
    for (int nb = 0; nb < 4; nb++)
#pragma unroll
      for (int r = 0; r < 4; r++) {
        float s = sv[nb][r] * scale;
        if (mt) {
          int kp = nb * 16 + lo;
          int qr = wave * 16 + hi * 4 + r;
          // note: qr is local within the 64-row block only when wave*16 fits;
          // global check reduces to local since tile bases are equal (kt==qb)
          if (kp > qr) s = -1e30f;
        }
        sv[nb][r] = s;
      }
    float mnew[4], rs[4];
#pragma unroll
    for (int r = 0; r < 4; r++) {
      float mx = fmaxf(fmaxf(sv[0][r], sv[1][r]), fmaxf(sv[2][r], sv[3][r]));
#pragma unroll
      for (int d = 1; d < 16; d <<= 1) mx = fmaxf(mx, __shfl_xor(mx, d, 64));
      mnew[r] = fmaxf(mrun[r], mx);
      float sc = __expf(mrun[r] - mnew[r]);
      lrun[r] *= sc;
#pragma unroll
      for (int db = 0; db < 4; db++) o[db][r] *= sc;
      mrun[r] = mnew[r];
      rs[r] = 0.f;
    }
    __syncthreads();  // previous P reads done
#pragma unroll
    for (int nb = 0; nb < 4; nb++)
#pragma unroll
      for (int r = 0; r < 4; r++) {
        float p = __expf(sv[nb][r] - mnew[r]);
        bf16 pb = (bf16)p;
        rs[r] += (float)pb;
        P[wave][hi * 4 + r][nb * 16 + lo] = pb;
      }
#pragma unroll
    for (int r = 0; r < 4; r++) {
      float t = rs[r];
#pragma unroll
      for (int d = 1; d < 16; d <<= 1) t += __shfl_xor(t, d, 64);
      lrun[r] += t;
    }
    __syncthreads();  // P writes visible
    bf16x8 pa[2];
#pragma unroll
    for (int ks = 0; ks < 2; ks++) pa[ks] = *(const bf16x8*)&P[wave][lo][ks * 32 + hi * 8];
#pragma unroll
    for (int db = 0; db < 4; db++)
#pragma unroll
      for (int ks = 0; ks < 2; ks++) {
        size_t voff = ((size_t)bh * 64 + db * 16 + lo) * 1024 + kt * 64 + ks * 32 + hi * 8;
        bf16x8 vf = *(const bf16x8*)(vT + voff);
        o[db] = mfma16(pa[ks], vf, o[db]);
      }
  }
  int b = bh >> 4, h = bh & 15;
#pragma unroll
  for (int db = 0; db < 4; db++)
#pragma unroll
    for (int r = 0; r < 4; r++) {
      float val = o[db][r] / lrun[r];
      size_t row = (size_t)b * 1024 + qb * 64 + wave * 16 + hi * 4 + r;
      ctx[row * 1024 + h * 64 + db * 16 + lo] = (bf16)val;
    }
}

// ---------------- host launcher ----------------

extern "C" void kernel_launch(void* const* d_in, const int* in_sizes, int n_in,
                              void* d_out, int out_size, void* d_ws, size_t ws_size,
                              hipStream_t stream) {
  (void)in_sizes; (void)n_in; (void)out_size; (void)ws_size;
  const float* x  = (const float*)d_in[0];
  const float* wq = (const float*)d_in[1];
  const float* wk = (const float*)d_in[2];
  const float* wv = (const float*)d_in[3];
  const float* wo = (const float*)d_in[4];
  const float* w1 = (const float*)d_in[5];
  const float* w2 = (const float*)d_in[6];
  const float* w3 = (const float*)d_in[7];
  const float* g1 = (const float*)d_in[8];
  const float* g2 = (const float*)d_in[9];
  float* out = (float*)d_out;

  char* ws = (char*)d_ws;
  size_t off = 0;
  auto alloc = [&](size_t bytes) {
    char* p = ws + off;
    off += (bytes + 255) & ~(size_t)255;
    return p;
  };
  const size_t MB2 = 1024u * 1024u * 2u;      // 1M bf16
  const size_t MB8 = 4096u * 1024u * 2u;      // 4M bf16
  void* WQH = alloc(MB2);  void* WQL = alloc(MB2);
  void* WKH = alloc(MB2);  void* WKL = alloc(MB2);
  void* WVH = alloc(MB2);  void* WOH = alloc(MB2);
  void* W1H = alloc(MB8);  void* W3H = alloc(MB8);  void* W2H = alloc(MB8);
  void* ROPE = alloc(32768u * 8u);
  void* Y1H = alloc(MB8);  void* Y1L = alloc(MB8);
  void* QH = alloc(MB8);   void* QL = alloc(MB8);
  void* KH = alloc(MB8);   void* KL = alloc(MB8);
  void* VT = alloc(MB8);
  void* CTX = alloc(MB8);
  void* Y2H = alloc(MB8);
  void* GLU = QH;  // 32MB alias over QH..KL (dead after flash)

  dim3 blk(256);
  auto cvt = [&](const float* src, void* hi_, void* lo_, int n) {
    int n4 = n / 4;
    cvt_kernel<<<dim3((n4 + 255) / 256), blk, 0, stream>>>(
        src, (unsigned short*)hi_, (unsigned short*)lo_, n4);
  };
  cvt(wq, WQH, WQL, 1024 * 1024);
  cvt(wk, WKH, WKL, 1024 * 1024);
  cvt(wv, WVH, nullptr, 1024 * 1024);
  cvt(wo, WOH, nullptr, 1024 * 1024);
  cvt(w1, W1H, nullptr, 4096 * 1024);
  cvt(w3, W3H, nullptr, 4096 * 1024);
  cvt(w2, W2H, nullptr, 4096 * 1024);

  rope_table_kernel<<<dim3(128), blk, 0, stream>>>((float2*)ROPE);

  rmsnorm_kernel<<<dim3(4096), blk, 0, stream>>>(x, g1, (unsigned short*)Y1H,
                                                 (unsigned short*)Y1L);

  gemm_qk_kernel<<<dim3(8, 32), blk, 0, stream>>>(
      (const bf16*)Y1H, (const bf16*)Y1L, (const bf16*)WQH, (const bf16*)WQL,
      (const float2*)ROPE, (bf16*)QH, (bf16*)QL);
  gemm_qk_kernel<<<dim3(8, 32), blk, 0, stream>>>(
      (const bf16*)Y1H, (const bf16*)Y1L, (const bf16*)WKH, (const bf16*)WKL,
      (const float2*)ROPE, (bf16*)KH, (bf16*)KL);

  gemm_nt<0><<<dim3(8, 32), blk, 0, stream>>>(
      (const bf16*)Y1H, (const bf16*)WVH, 4096, 1024, 1024,
      nullptr, (bf16*)VT, nullptr, nullptr);

  flash_kernel<<<dim3(16, 64), blk, 0, stream>>>(
      (const bf16*)QH, (const bf16*)QL, (const bf16*)KH, (const bf16*)KL,
      (const bf16*)VT, (bf16*)CTX);

  gemm_nt<1><<<dim3(8, 32), blk, 0, stream>>>(
      (const bf16*)CTX, (const bf16*)WOH, 4096, 1024, 1024,
      out, nullptr, x, nullptr);

  rmsnorm_kernel<<<dim3(4096), blk, 0, stream>>>(out, g2, (unsigned short*)Y2H, nullptr);

  gemm_nt<2><<<dim3(32, 32), blk, 0, stream>>>(
      (const bf16*)Y2H, (const bf16*)W1H, 4096, 4096, 1024,
      nullptr, (bf16*)GLU, nullptr, nullptr);
  gemm_nt<3><<<dim3(32, 32), blk, 0, stream>>>(
      (const bf16*)Y2H, (const bf16*)W3H, 4096, 4096, 1024,
      nullptr, nullptr, nullptr, (bf16*)GLU);
  gemm_nt<4><<<dim3(8, 32), blk, 0, stream>>>(
      (const bf16*)GLU, (const bf16*)W2H, 4096, 1024, 4096,
      out, nullptr, nullptr, nullptr);
}

// Round 2
// 362.086 us; speedup vs baseline: 1.4956x; 1.4956x over previous
//
#include <hip/hip_runtime.h>

typedef __bf16 bf16;
typedef __attribute__((ext_vector_type(8))) __bf16 bf16x8;
typedef __attribute__((ext_vector_type(4))) float f32x4;

static __device__ __forceinline__ int swz4(int r) { return (r & 3) ^ ((r >> 2) & 3); }

static __device__ __forceinline__ void async_cp16(void* lds, const void* g) {
  __builtin_amdgcn_global_load_lds((__attribute__((address_space(1))) void*)g,
                                   (__attribute__((address_space(3))) void*)lds,
                                   16, 0, 0);
}

static __device__ __forceinline__ f32x4 mfma16(bf16x8 a, bf16x8 b, f32x4 c) {
  return __builtin_amdgcn_mfma_f32_16x16x32_bf16(a, b, c, 0, 0, 0);
}

static __device__ __forceinline__ unsigned short bfbits(float f) {
  bf16 b = (bf16)f;
  return __builtin_bit_cast(unsigned short, b);
}

// ---------------- small kernels ----------------

extern "C" __global__ void cvt_kernel(const float* __restrict__ src,
                                      unsigned short* __restrict__ hi,
                                      unsigned short* __restrict__ lo, int n4) {
  int i = blockIdx.x * 256 + threadIdx.x;
  if (i >= n4) return;
  float4 v = ((const float4*)src)[i];
  bf16 b0 = (bf16)v.x, b1 = (bf16)v.y, b2 = (bf16)v.z, b3 = (bf16)v.w;
  ushort4 oh;
  oh.x = __builtin_bit_cast(unsigned short, b0);
  oh.y = __builtin_bit_cast(unsigned short, b1);
  oh.z = __builtin_bit_cast(unsigned short, b2);
  oh.w = __builtin_bit_cast(unsigned short, b3);
  ((ushort4*)hi)[i] = oh;
  if (lo) {
    ushort4 ol;
    ol.x = bfbits(v.x - (float)b0);
    ol.y = bfbits(v.y - (float)b1);
    ol.z = bfbits(v.z - (float)b2);
    ol.w = bfbits(v.w - (float)b3);
    ((ushort4*)lo)[i] = ol;
  }
}

extern "C" __global__ void rope_table_kernel(float2* __restrict__ rope) {
  int idx = blockIdx.x * 256 + threadIdx.x; // 32768
  int s = idx >> 5, i = idx & 31;
  float inv_freq = powf(10000.0f, -(2.0f * (float)i) / 64.0f);
  float ang = (float)s * inv_freq;
  float2 cs;
  cs.x = cosf(ang);
  cs.y = sinf(ang);
  rope[idx] = cs;
}

extern "C" __global__ __launch_bounds__(256) void rmsnorm_kernel(
    const float* __restrict__ x, const float* __restrict__ g,
    unsigned short* __restrict__ yhi, unsigned short* __restrict__ ylo) {
  int row = blockIdx.x;
  int t = threadIdx.x;
  const float4 xv = *(const float4*)(x + (size_t)row * 1024 + t * 4);
  float ss = xv.x * xv.x + xv.y * xv.y + xv.z * xv.z + xv.w * xv.w;
#pragma unroll
  for (int d = 1; d < 64; d <<= 1) ss += __shfl_xor(ss, d, 64);
  __shared__ float red[4];
  if ((t & 63) == 0) red[t >> 6] = ss;
  __syncthreads();
  float tot = red[0] + red[1] + red[2] + red[3];
  float inv = 1.0f / sqrtf(tot * (1.0f / 1024.0f) + 1e-5f);
  const float4 gv = *(const float4*)(g + t * 4);
  float y0 = xv.x * gv.x * inv, y1 = xv.y * gv.y * inv;
  float y2 = xv.z * gv.z * inv, y3 = xv.w * gv.w * inv;
  bf16 b0 = (bf16)y0, b1 = (bf16)y1, b2 = (bf16)y2, b3 = (bf16)y3;
  ushort4 oh;
  oh.x = __builtin_bit_cast(unsigned short, b0);
  oh.y = __builtin_bit_cast(unsigned short, b1);
  oh.z = __builtin_bit_cast(unsigned short, b2);
  oh.w = __builtin_bit_cast(unsigned short, b3);
  ((ushort4*)yhi)[(size_t)row * 256 + t] = oh;
  if (ylo) {
    ushort4 ol;
    ol.x = bfbits(y0 - (float)b0);
    ol.y = bfbits(y1 - (float)b1);
    ol.z = bfbits(y2 - (float)b2);
    ol.w = bfbits(y3 - (float)b3);
    ((ushort4*)ylo)[(size_t)row * 256 + t] = ol;
  }
}

// ---------------- GEMM: C[M,N] = A[M,K] * B[N,K]^T, 128x128 tile, BK=32 ----------------
// EPI 0: vT store (bf16, transposed per-head v)
// EPI 1: + resF -> f32 outF
// EPI 4: outF[idx] += acc (f32 in/out)
template <int EPI>
__global__ __launch_bounds__(256, 2) void gemm_nt(
    const bf16* __restrict__ A, const bf16* __restrict__ B, int M, int N, int K,
    float* __restrict__ outF, bf16* __restrict__ outB,
    const float* __restrict__ resF) {
  __shared__ alignas(16) bf16 As[128 * 32];
  __shared__ alignas(16) bf16 Bs[128 * 32];
  const int tid = threadIdx.x;
  const int lane = tid & 63, wave = tid >> 6;
  const int lo = lane & 15, hi = lane >> 4;
  const int wm = wave >> 1, wn = wave & 1;
  const size_t tm = (size_t)blockIdx.y * 128, tn = (size_t)blockIdx.x * 128;
  f32x4 acc[4][4] = {};
  for (int k0 = 0; k0 < K; k0 += 32) {
    __syncthreads();
#pragma unroll
    for (int i2 = 0; i2 < 2; i2++) {
      int p = tid + 256 * i2;
      int row = p >> 2, kcp = p & 3;
      int kcl = kcp ^ swz4(row);
      async_cp16((char*)As + (size_t)p * 16, A + (tm + row) * (size_t)K + k0 + kcl * 8);
      async_cp16((char*)Bs + (size_t)p * 16, B + (tn + row) * (size_t)K + k0 + kcl * 8);
    }
    __syncthreads();
    bf16x8 fa[4], fb[4];
#pragma unroll
    for (int i = 0; i < 4; i++) {
      int ra = wm * 64 + i * 16 + lo;
      fa[i] = *(const bf16x8*)((const char*)As + ra * 64 + ((hi ^ swz4(ra)) << 4));
      int rb = wn * 64 + i * 16 + lo;
      fb[i] = *(const bf16x8*)((const char*)Bs + rb * 64 + ((hi ^ swz4(rb)) << 4));
    }
    __builtin_amdgcn_s_setprio(1);
#pragma unroll
    for (int i = 0; i < 4; i++)
#pragma unroll
      for (int j = 0; j < 4; j++) acc[i][j] = mfma16(fa[i], fb[j], acc[i][j]);
    __builtin_amdgcn_s_setprio(0);
  }
#pragma unroll
  for (int i = 0; i < 4; i++)
#pragma unroll
    for (int j = 0; j < 4; j++)
#pragma unroll
      for (int r = 0; r < 4; r++) {
        size_t m = tm + wm * 64 + i * 16 + hi * 4 + r;
        size_t n = tn + wn * 64 + j * 16 + lo;
        float v = acc[i][j][r];
        if constexpr (EPI == 0) {
          size_t idx = (((m >> 10) * 16 + (n >> 6)) * 64 + (n & 63)) * 1024 + (m & 1023);
          outB[idx] = (bf16)v;
        } else if constexpr (EPI == 1) {
          size_t idx = m * (size_t)N + n;
          outF[idx] = v + resF[idx];
        } else {
          size_t idx = m * (size_t)N + n;
          outF[idx] = outF[idx] + v;
        }
      }
}

// ---------------- fused SwiGLU FFN up-projection: G = silu(A*B1^T) * (A*B3^T) ----------------
extern "C" __global__ __launch_bounds__(256, 2) void gemm_glu_kernel(
    const bf16* __restrict__ A, const bf16* __restrict__ B1,
    const bf16* __restrict__ B3, bf16* __restrict__ G) {
  __shared__ alignas(16) bf16 As[128 * 32];
  __shared__ alignas(16) bf16 B1s[128 * 32];
  __shared__ alignas(16) bf16 B3s[128 * 32];
  const int tid = threadIdx.x;
  const int lane = tid & 63, wave = tid >> 6;
  const int lo = lane & 15, hi = lane >> 4;
  const int wm = wave >> 1, wn = wave & 1;
  const size_t tm = (size_t)blockIdx.y * 128, tn = (size_t)blockIdx.x * 128;
  const int K = 1024, N = 4096;
  f32x4 acc1[4][4] = {};
  f32x4 acc3[4][4] = {};
  for (int k0 = 0; k0 < K; k0 += 32) {
    __syncthreads();
#pragma unroll
    for (int i2 = 0; i2 < 2; i2++) {
      int p = tid + 256 * i2;
      int row = p >> 2;
      int kcl = (p & 3) ^ swz4(row);
      async_cp16((char*)As + (size_t)p * 16, A + (tm + row) * (size_t)K + k0 + kcl * 8);
      async_cp16((char*)B1s + (size_t)p * 16, B1 + (tn + row) * (size_t)K + k0 + kcl * 8);
      async_cp16((char*)B3s + (size_t)p * 16, B3 + (tn + row) * (size_t)K + k0 + kcl * 8);
    }
    __syncthreads();
    bf16x8 fa[4], f1[4], f3[4];
#pragma unroll
    for (int i = 0; i < 4; i++) {
      int ra = wm * 64 + i * 16 + lo;
      int oa = ra * 64 + ((hi ^ swz4(ra)) << 4);
      fa[i] = *(const bf16x8*)((const char*)As + oa);
      int rb = wn * 64 + i * 16 + lo;
      int ob = rb * 64 + ((hi ^ swz4(rb)) << 4);
      f1[i] = *(const bf16x8*)((const char*)B1s + ob);
      f3[i] = *(const bf16x8*)((const char*)B3s + ob);
    }
    __builtin_amdgcn_s_setprio(1);
#pragma unroll
    for (int i = 0; i < 4; i++)
#pragma unroll
      for (int j = 0; j < 4; j++) {
        acc1[i][j] = mfma16(fa[i], f1[j], acc1[i][j]);
        acc3[i][j] = mfma16(fa[i], f3[j], acc3[i][j]);
      }
    __builtin_amdgcn_s_setprio(0);
  }
#pragma unroll
  for (int i = 0; i < 4; i++)
#pragma unroll
    for (int j = 0; j < 4; j++)
#pragma unroll
      for (int r = 0; r < 4; r++) {
        size_t m = tm + wm * 64 + i * 16 + hi * 4 + r;
        size_t n = tn + wn * 64 + j * 16 + lo;
        float v1 = acc1[i][j][r], v3 = acc3[i][j][r];
        float glu = v1 / (1.0f + __expf(-v1)) * v3;
        G[m * (size_t)N + n] = (bf16)glu;
      }
}

// ---------------- split-precision q/k projection GEMM with fused RoPE ----------------
// z=0: Q (BhQ/BlQ -> OhQ/OlQ), z=1: K
extern "C" __global__ __launch_bounds__(256, 2) void gemm_qk_kernel(
    const bf16* __restrict__ Ah, const bf16* __restrict__ Al,
    const bf16* __restrict__ BhQ, const bf16* __restrict__ BlQ,
    const bf16* __restrict__ BhK, const bf16* __restrict__ BlK,
    const float2* __restrict__ rope,
    bf16* __restrict__ OhQ, bf16* __restrict__ OlQ,
    bf16* __restrict__ OhK, bf16* __restrict__ OlK) {
  const bf16* Bh = blockIdx.z ? BhK : BhQ;
  const bf16* Bl = blockIdx.z ? BlK : BlQ;
  bf16* Oh = blockIdx.z ? OhK : OhQ;
  bf16* Ol = blockIdx.z ? OlK : OlQ;
  __shared__ alignas(16) bf16 Ahs[128 * 32], Als[128 * 32], Bhs[128 * 32], Bls[128 * 32];
  const int tid = threadIdx.x;
  const int lane = tid & 63, wave = tid >> 6;
  const int lo = lane & 15, hi = lane >> 4;
  const int wm = wave >> 1, wn = wave & 1;
  const size_t tm = (size_t)blockIdx.y * 128, tn = (size_t)blockIdx.x * 128;
  const int K = 1024;
  f32x4 acc[4][4] = {};
  for (int k0 = 0; k0 < K; k0 += 32) {
    __syncthreads();
#pragma unroll
    for (int i2 = 0; i2 < 2; i2++) {
      int p = tid + 256 * i2;
      int row = p >> 2;
      int kcl = (p & 3) ^ swz4(row);
      size_t ga = (tm + row) * (size_t)K + k0 + kcl * 8;
      size_t gb = (tn + row) * (size_t)K + k0 + kcl * 8;
      async_cp16((char*)Ahs + (size_t)p * 16, Ah + ga);
      async_cp16((char*)Als + (size_t)p * 16, Al + ga);
      async_cp16((char*)Bhs + (size_t)p * 16, Bh + gb);
      async_cp16((char*)Bls + (size_t)p * 16, Bl + gb);
    }
    __syncthreads();
    bf16x8 fah[4], fal[4], fbh[4], fbl[4];
#pragma unroll
    for (int i = 0; i < 4; i++) {
      int ra = wm * 64 + i * 16 + lo;
      int oa = ra * 64 + ((hi ^ swz4(ra)) << 4);
      fah[i] = *(const bf16x8*)((const char*)Ahs + oa);
      fal[i] = *(const bf16x8*)((const char*)Als + oa);
      int rb = wn * 64 + i * 16 + lo;
      int ob = rb * 64 + ((hi ^ swz4(rb)) << 4);
      fbh[i] = *(const bf16x8*)((const char*)Bhs + ob);
      fbl[i] = *(const bf16x8*)((const char*)Bls + ob);
    }
    __builtin_amdgcn_s_setprio(1);
#pragma unroll
    for (int i = 0; i < 4; i++)
#pragma unroll
      for (int j = 0; j < 4; j++) {
        f32x4 a = acc[i][j];
        a = mfma16(fah[i], fbh[j], a);
        a = mfma16(fah[i], fbl[j], a);
        a = mfma16(fal[i], fbh[j], a);
        acc[i][j] = a;
      }
    __builtin_amdgcn_s_setprio(0);
  }
#pragma unroll
  for (int i = 0; i < 4; i++)
#pragma unroll
    for (int j = 0; j < 4; j++)
#pragma unroll
      for (int r = 0; r < 4; r++) {
        float v = acc[i][j][r];
        float vp = __shfl_xor(v, 1, 64);
        size_t m = tm + wm * 64 + i * 16 + hi * 4 + r;
        size_t n = tn + wn * 64 + j * 16 + lo;
        int s = (int)(m & 1023);
        int pi = (int)((n & 63) >> 1);
        float2 cs = rope[s * 32 + pi];
        float res = (n & 1) ? (vp * cs.y + v * cs.x) : (v * cs.x - vp * cs.y);
        size_t idx = (((m >> 10) * 16 + (n >> 6)) * 1024 + (m & 1023)) * 64 + (n & 63);
        bf16 hb = (bf16)res;
        Oh[idx] = hb;
        Ol[idx] = (bf16)(res - (float)hb);
      }
}

// ---------------- flash attention (causal), LDS-staged K/V, 64-row Q block, 4 waves ----------------
// q/k: (b,h,s,64) bf16 hi/lo ; vT: (b,h,64,s) bf16 ; ctx out: (b,s,1024) bf16
extern "C" __global__ __launch_bounds__(256, 4) void flash_kernel(
    const bf16* __restrict__ qhi, const bf16* __restrict__ qlo,
    const bf16* __restrict__ khi, const bf16* __restrict__ klo,
    const bf16* __restrict__ vT, bf16* __restrict__ ctx) {
  const int bid = blockIdx.x;       // 1024 blocks, qb varies with bid>>6 so a CU's
  const int qb = bid >> 6;          // 4 resident blocks get qb {q,q+4,q+8,q+12}
  const int bh = bid & 63;
  const int tid = threadIdx.x;
  const int wave = tid >> 6, lane = tid & 63;
  const int lo = lane & 15, hi = lane >> 4;

  __shared__ alignas(16) bf16 Ksh[2][64][32];  // [ks-half][k-row][k-col], swz4-chunked
  __shared__ alignas(16) bf16 Ksl[2][64][32];
  __shared__ alignas(16) bf16 Vs[2][64][32];   // [ks-half][d-row][k-col]
  __shared__ alignas(16) bf16 P[4][16][72];    // per-wave private transpose buffer

  size_t qoff = ((size_t)bh * 1024 + qb * 64 + wave * 16 + lo) * 64;
  bf16x8 qh[2], ql[2];
#pragma unroll
  for (int ks = 0; ks < 2; ks++) {
    qh[ks] = *(const bf16x8*)(qhi + qoff + ks * 32 + hi * 8);
    ql[ks] = *(const bf16x8*)(qlo + qoff + ks * 32 + hi * 8);
  }

  const int srow = tid >> 2;                 // staging row 0..63 (same for both halves)
  const int scl = (tid & 3) ^ swz4(srow);    // pre-swizzled source chunk
  const size_t kgb = (size_t)bh * 1024 * 64;
  const size_t vgb = ((size_t)bh * 64 + srow) * 1024;

  float mrun[4] = {-1e30f, -1e30f, -1e30f, -1e30f};
  float lrun[4] = {0.f, 0.f, 0.f, 0.f};
  f32x4 o[4] = {};
  const float scale = 0.125f;

  for (int kt = 0; kt <= qb; kt++) {
    __syncthreads();  // all waves done reading previous K/V tiles
#pragma unroll
    for (int i = 0; i < 2; i++) {
      int p = tid + 256 * i;
      size_t gk = kgb + (size_t)(kt * 64 + srow) * 64 + i * 32 + scl * 8;
      async_cp16((char*)Ksh + (size_t)p * 16, khi + gk);
      async_cp16((char*)Ksl + (size_t)p * 16, klo + gk);
      async_cp16((char*)Vs + (size_t)p * 16, vT + vgb + kt * 64 + i * 32 + scl * 8);
    }
    __syncthreads();  // staged data visible

    f32x4 sv[4];
    __builtin_amdgcn_s_setprio(1);
#pragma unroll
    for (int nb = 0; nb < 4; nb++) {
      f32x4 a = {0.f, 0.f, 0.f, 0.f};
#pragma unroll
      for (int ks = 0; ks < 2; ks++) {
        int row = nb * 16 + lo;
        int off16 = (ks * 64 + row) * 4 + (hi ^ swz4(row));
        bf16x8 kh = *(const bf16x8*)((const char*)Ksh + off16 * 16);
        bf16x8 kl = *(const bf16x8*)((const char*)Ksl + off16 * 16);
        a = mfma16(qh[ks], kh, a);
        a = mfma16(qh[ks], kl, a);
        a = mfma16(ql[ks], kh, a);
      }
      sv[nb] = a;
    }
    __builtin_amdgcn_s_setprio(0);

    const bool mt = (kt == qb);
#pragma unroll
    for (int nb = 0; nb < 4; nb++)
#pragma unroll
      for (int r = 0; r < 4; r++) {
        float s = sv[nb][r] * scale;
        if (mt) {
          int kp = nb * 16 + lo;
          int qr = wave * 16 + hi * 4 + r;
          if (kp > qr) s = -1e30f;
        }
        sv[nb][r] = s;
      }
    float mnew[4], rs[4];
#pragma unroll
    for (int r = 0; r < 4; r++) {
      float mx = fmaxf(fmaxf(sv[0][r], sv[1][r]), fmaxf(sv[2][r], sv[3][r]));
#pragma unroll
      for (int d = 1; d < 16; d <<= 1) mx = fmaxf(mx, __shfl_xor(mx, d, 64));
      mnew[r] = fmaxf(mrun[r], mx);
      float sc = __expf(mrun[r] - mnew[r]);
      lrun[r] *= sc;
#pragma unroll
      for (int db = 0; db < 4; db++) o[db][r] *= sc;
      mrun[r] = mnew[r];
      rs[r] = 0.f;
    }
    // P write+read is per-wave private LDS: no block barrier needed
#pragma unroll
    for (int nb = 0; nb < 4; nb++)
#pragma unroll
      for (int r = 0; r < 4; r++) {
        float p = __expf(sv[nb][r] - mnew[r]);
        bf16 pb = (bf16)p;
        rs[r] += (float)pb;
        P[wave][hi * 4 + r][nb * 16 + lo] = pb;
      }
#pragma unroll
    for (int r = 0; r < 4; r++) {
      float t = rs[r];
#pragma unroll
      for (int d = 1; d < 16; d <<= 1) t += __shfl_xor(t, d, 64);
      lrun[r] += t;
    }
    bf16x8 pa[2];
#pragma unroll
    for (int ks = 0; ks < 2; ks++) pa[ks] = *(const bf16x8*)&P[wave][lo][ks * 32 + hi * 8];
    __builtin_amdgcn_s_setprio(1);
#pragma unroll
    for (int db = 0; db < 4; db++)
#pragma unroll
      for (int ks = 0; ks < 2; ks++) {
        int row = db * 16 + lo;
        int off16 = (ks * 64 + row) * 4 + (hi ^ swz4(row));
        bf16x8 vf = *(const bf16x8*)((const char*)Vs + off16 * 16);
        o[db] = mfma16(pa[ks], vf, o[db]);
      }
    __builtin_amdgcn_s_setprio(0);
  }
  int b = bh >> 4, h = bh & 15;
#pragma unroll
  for (int db = 0; db < 4; db++)
#pragma unroll
    for (int r = 0; r < 4; r++) {
      float val = o[db][r] / lrun[r];
      size_t row = (size_t)b * 1024 + qb * 64 + wave * 16 + hi * 4 + r;
      ctx[row * 1024 + h * 64 + db * 16 + lo] = (bf16)val;
    }
}

// ---------------- host launcher ----------------

extern "C" void kernel_launch(void* const* d_in, const int* in_sizes, int n_in,
                              void* d_out, int out_size, void* d_ws, size_t ws_size,
                              hipStream_t stream) {
  (void)in_sizes; (void)n_in; (void)out_size; (void)ws_size;
  const float* x  = (const float*)d_in[0];
  const float* wq = (const float*)d_in[1];
  const float* wk = (const float*)d_in[2];
  const float* wv = (const float*)d_in[3];
  const float* wo = (const float*)d_in[4];
  const float* w1 = (const float*)d_in[5];
  const float* w2 = (const float*)d_in[6];
  const float* w3 = (const float*)d_in[7];
  const float* g1 = (const float*)d_in[8];
  const float* g2 = (const float*)d_in[9];
  float* out = (float*)d_out;

  char* ws = (char*)d_ws;
  size_t off = 0;
  auto alloc = [&](size_t bytes) {
    char* p = ws + off;
    off += (bytes + 255) & ~(size_t)255;
    return p;
  };
  const size_t MB2 = 1024u * 1024u * 2u;      // 1M bf16
  const size_t MB8 = 4096u * 1024u * 2u;      // 4M bf16
  void* WQH = alloc(MB2);  void* WQL = alloc(MB2);
  void* WKH = alloc(MB2);  void* WKL = alloc(MB2);
  void* WVH = alloc(MB2);  void* WOH = alloc(MB2);
  void* W1H = alloc(MB8);  void* W3H = alloc(MB8);  void* W2H = alloc(MB8);
  void* ROPE = alloc(32768u * 8u);
  void* Y1H = alloc(MB8);  void* Y1L = alloc(MB8);
  void* QH = alloc(MB8);   void* QL = alloc(MB8);
  void* KH = alloc(MB8);   void* KL = alloc(MB8);
  void* VT = alloc(MB8);
  void* CTX = alloc(MB8);
  void* Y2H = alloc(MB8);
  void* GLU = QH;  // 32MB alias over QH,QL,KH,KL (dead after flash)

  dim3 blk(256);
  auto cvt = [&](const float* src, void* hi_, void* lo_, int n) {
    int n4 = n / 4;
    cvt_kernel<<<dim3((n4 + 255) / 256), blk, 0, stream>>>(
        src, (unsigned short*)hi_, (unsigned short*)lo_, n4);
  };
  cvt(wq, WQH, WQL, 1024 * 1024);
  cvt(wk, WKH, WKL, 1024 * 1024);
  cvt(wv, WVH, nullptr, 1024 * 1024);
  cvt(wo, WOH, nullptr, 1024 * 1024);
  cvt(w1, W1H, nullptr, 4096 * 1024);
  cvt(w3, W3H, nullptr, 4096 * 1024);
  cvt(w2, W2H, nullptr, 4096 * 1024);

  rope_table_kernel<<<dim3(128), blk, 0, stream>>>((float2*)ROPE);

  rmsnorm_kernel<<<dim3(4096), blk, 0, stream>>>(x, g1, (unsigned short*)Y1H,
                                                 (unsigned short*)Y1L);

  gemm_qk_kernel<<<dim3(8, 32, 2), blk, 0, stream>>>(
      (const bf16*)Y1H, (const bf16*)Y1L,
      (const bf16*)WQH, (const bf16*)WQL, (const bf16*)WKH, (const bf16*)WKL,
      (const float2*)ROPE,
      (bf16*)QH, (bf16*)QL, (bf16*)KH, (bf16*)KL);

  gemm_nt<0><<<dim3(8, 32), blk, 0, stream>>>(
      (const bf16*)Y1H, (const bf16*)WVH, 4096, 1024, 1024,
      nullptr, (bf16*)VT, nullptr);

  flash_kernel<<<dim3(1024), blk, 0, stream>>>(
      (const bf16*)QH, (const bf16*)QL, (const bf16*)KH, (const bf16*)KL,
      (const bf16*)VT, (bf16*)CTX);

  gemm_nt<1><<<dim3(8, 32), blk, 0, stream>>>(
      (const bf16*)CTX, (const bf16*)WOH, 4096, 1024, 1024,
      out, nullptr, x);

  rmsnorm_kernel<<<dim3(4096), blk, 0, stream>>>(out, g2, (unsigned short*)Y2H, nullptr);

  gemm_glu_kernel<<<dim3(32, 32), blk, 0, stream>>>(
      (const bf16*)Y2H, (const bf16*)W1H, (const bf16*)W3H, (bf16*)GLU);

  gemm_nt<4><<<dim3(8, 32), blk, 0, stream>>>(
      (const bf16*)GLU, (const bf16*)W2H, 4096, 1024, 4096,
      out, nullptr, nullptr);
}